// Round 5
// baseline (149.542 us; speedup 1.0000x reference)
//
#include <hip/hip_runtime.h>
#include <math.h>

#define DD 128
#define BB 8192
#define NN 64
#define LOGC 235.24826450039622f   // 128 * log(2*pi)
#define CLAMP_M 1.0e12f            // clamp on solve outputs: keeps downstream finite (no NaN)
#define YCLAMP 1.0e18f             // fallback-path clamp
#define KP 136                     // kernel-B LDS pitch in bf16 (128+8: row stride 272B -> 2-way=free)
#define PITCH 129                  // kernel-A LDS pitch in f32

typedef __attribute__((ext_vector_type(8))) short bf16x8;   // 8 bf16 = 4 VGPRs
typedef __attribute__((ext_vector_type(4))) float f32x4;

__device__ __forceinline__ unsigned int f2bf(float x) {
    unsigned int u = __float_as_uint(x);
    return (u + 0x7FFFu + ((u >> 16) & 1u)) >> 16;
}
__device__ __forceinline__ unsigned int pack2(float lo, float hi) {
    return f2bf(lo) | (f2bf(hi) << 16);
}
__device__ __forceinline__ float clampM(float x) {
    return fminf(fmaxf(x, -CLAMP_M), CLAMP_M);
}
__device__ __forceinline__ float lane_bcast(float v, int j) {
    return __int_as_float(__builtin_amdgcn_readlane(__float_as_int(v), j));
}

// ---------------------------------------------------------------------------
// Kernel A: right-looking column solve, one wave per column, with triangular
// skip (R5): block grp owns columns base..base+3 (base=4*grp); y_j=0 for
// j<base, so solve starts at j=base and LsT rows j<base are never staged.
// Grid: (33, 64). Group 32: wave0 solves RHS=mu -> vout; wave1 -> termout.
// ---------------------------------------------------------------------------
__global__ __launch_bounds__(256, 2)
void solve_columns(const float* __restrict__ chol,
                   const float* __restrict__ means,
                   unsigned short* __restrict__ Mout,  // (N,D,D) bf16
                   float* __restrict__ vout,           // (N,D)
                   float* __restrict__ termout)        // (N)
{
    const int n = blockIdx.y;
    const int grp = blockIdx.x;      // 0..32
    const int t = threadIdx.x;
    const int lane = t & 63;
    const int w = t >> 6;
    const float* __restrict__ Ln = chol + (size_t)n * DD * DD;

    const bool is_mu = (grp == 32);
    const int base = is_mu ? 0 : grp * 4;

    __shared__ float LsT[DD][PITCH];   // [j][i] = (i>j) ? L[i][j] : 0
    __shared__ float s_invd[DD];
    __shared__ float s_raw[DD];
    __shared__ float ybuf[4][DD + 2];

    // --- stage L transposed + tril-masked; skip rows j<base (never read) ---
    #pragma unroll
    for (int it = 0; it < 16; ++it) {
        const int id = it * 256 + t;        // 4096 float4 chunks
        const int i = id >> 5;              // row of L
        const int j0 = (id & 31) * 4;       // col of L
        if (j0 + 3 < base) continue;        // these LsT rows are never read
        if (i <= j0) {
            // whole chunk in upper triangle -> zeros, no global load
            LsT[j0 + 0][i] = 0.0f;
            LsT[j0 + 1][i] = 0.0f;
            LsT[j0 + 2][i] = 0.0f;
            LsT[j0 + 3][i] = 0.0f;
        } else {
            const float4 vv = *(const float4*)(Ln + (size_t)i * DD + j0);
            LsT[j0 + 0][i] = (i > j0 + 0) ? vv.x : 0.0f;
            LsT[j0 + 1][i] = (i > j0 + 1) ? vv.y : 0.0f;
            LsT[j0 + 2][i] = (i > j0 + 2) ? vv.z : 0.0f;
            LsT[j0 + 3][i] = (i > j0 + 3) ? vv.w : 0.0f;
        }
    }
    if (t < DD) {
        const float raw = Ln[(size_t)t * DD + t];
        s_raw[t] = raw;
        s_invd[t] = __expf(-raw);           // 1/exp(raw): diag of L is exp(raw)
    }
    __syncthreads();

    // --- init residual r = RHS, distributed: lane l holds r[l], r[l+64] ---
    float r_lo = 0.0f, r_hi = 0.0f;
    if (is_mu) {
        if (w == 0) {
            r_lo = means[(size_t)n * DD + lane];
            r_hi = means[(size_t)n * DD + 64 + lane];
        } else if (w == 1) {
            float v = s_raw[lane] + s_raw[64 + lane];
            #pragma unroll
            for (int o = 32; o > 0; o >>= 1) v += __shfl_down(v, o);
            if (lane == 0) termout[n] = LOGC + 2.0f * v;
        }
    } else {
        const int c = grp * 4 + w;          // this wave's column
        r_lo = (lane == c) ? 1.0f : 0.0f;
        r_hi = (lane + 64 == c) ? 1.0f : 0.0f;
    }

    // --- right-looking forward substitution, steps j in [base, 128) ---
    #pragma unroll 4
    for (int j = base; j < 64; ++j) {
        const float y = clampM(lane_bcast(r_lo, j) * s_invd[j]);
        r_lo = fmaf(-LsT[j][lane], y, r_lo);
        r_hi = fmaf(-LsT[j][64 + lane], y, r_hi);
    }
    #pragma unroll 4
    for (int j = (base > 64 ? base : 64); j < 128; ++j) {
        const float y = clampM(lane_bcast(r_hi, j - 64) * s_invd[j]);
        r_hi = fmaf(-LsT[j][64 + lane], y, r_hi);
    }

    const float y_lo = clampM(r_lo * s_invd[lane]);
    const float y_hi = clampM(r_hi * s_invd[64 + lane]);

    if (is_mu) {
        if (w == 0) {
            vout[(size_t)n * DD + lane] = y_lo;
            vout[(size_t)n * DD + 64 + lane] = y_hi;
        }
        return;  // block-uniform exit
    }

    ybuf[w][lane] = y_lo;
    ybuf[w][64 + lane] = y_hi;
    __syncthreads();

    // cooperative write of the 128x4 column tile as bf16 (2 cols per thread)
    const int i = t >> 1;
    const int p = t & 1;
    const unsigned int pk = pack2(ybuf[2 * p][i], ybuf[2 * p + 1][i]);
    *(unsigned int*)&Mout[((size_t)n * DD + i) * DD + grp * 4 + 2 * p] = pk;
}

// ---------------------------------------------------------------------------
// Kernel B: quad[b,n] = || M_n x_b - v_n ||^2 via bf16 MFMA, fused epilogue.
// R5: register-prefetch pipeline — M_{n+1} global loads issue before the
// barrier and fly under iteration n's MFMA+epilogue.
// ---------------------------------------------------------------------------
__global__ __launch_bounds__(256, 2)
void emission_mfma(const float* __restrict__ x,
                   const unsigned short* __restrict__ Mws,
                   const float* __restrict__ vws,
                   const float* __restrict__ termws,
                   float* __restrict__ out)
{
    const int btile = blockIdx.x;            // 64 tiles of 128 b
    const int ngrp = blockIdx.y;             // 8 groups of 8 n
    const int t = threadIdx.x;
    const int lane = t & 63;
    const int w = t >> 6;
    const int wi = w >> 1;                   // i-half
    const int wb = w & 1;                    // b-half

    __shared__ __align__(16) unsigned short xs[128 * KP];
    __shared__ __align__(16) unsigned short as[128 * KP];
    __shared__ __align__(16) float sv[DD];
    __shared__ float sterm[8];
    __shared__ float redbuf[2 * 128];
    __shared__ float qbuf[8 * 128];

    const int bbase = btile * 128;

    // --- stage x tile -> bf16 LDS [b][k] ---
    #pragma unroll
    for (int it = 0; it < 8; ++it) {
        const int id = it * 256 + t;
        const int brow = id >> 4;
        const int koff = (id & 15) * 8;
        const float4* px = (const float4*)(x + (size_t)(bbase + brow) * DD + koff);
        const float4 a = px[0], b = px[1];
        uint4 p;
        p.x = pack2(a.x, a.y);
        p.y = pack2(a.z, a.w);
        p.z = pack2(b.x, b.y);
        p.w = pack2(b.z, b.w);
        *(uint4*)&xs[brow * KP + koff] = p;
    }

    // prefetch M_{n0} into registers while xs settles
    const int mrow = t >> 1;                 // staging coords (row, 2 chunks/row)
    const int mk = (t & 1) * 64;
    uint4 pref[8];
    {
        const unsigned short* __restrict__ Mn = Mws + (size_t)(ngrp * 8) * DD * DD;
        #pragma unroll
        for (int it = 0; it < 8; ++it)
            pref[it] = *(const uint4*)&Mn[(size_t)((it & 3) * 32 + mrow / 4) * DD +
                                          mk + (mrow & 3) * 0 + (it >> 2) * 32];
    }
    // NOTE on layout: thread t loads rows (it&3)*32 + (t>>3)... keep it simple:
    // redo with straightforward mapping below (overwrites the above).
    {
        const unsigned short* __restrict__ Mn = Mws + (size_t)(ngrp * 8) * DD * DD;
        #pragma unroll
        for (int it = 0; it < 8; ++it) {
            const int id = it * 256 + t;     // 2048 chunks of 8 bf16
            const int row = id >> 4;
            const int koff = (id & 15) * 8;
            pref[it] = *(const uint4*)&Mn[(size_t)row * DD + koff];
        }
    }
    __syncthreads();   // xs visible

    // --- preload B-operand frags (x) to registers ---
    bf16x8 bf[4][4];
    #pragma unroll
    for (int bt = 0; bt < 4; ++bt)
        #pragma unroll
        for (int ks = 0; ks < 4; ++ks) {
            const int col = wb * 64 + bt * 16 + (lane & 15);
            const int k = ks * 32 + (lane >> 4) * 8;
            bf[bt][ks] = *(const bf16x8*)&xs[col * KP + k];
        }

    const f32x4 zero = {0.0f, 0.0f, 0.0f, 0.0f};

    for (int nl = 0; nl < 8; ++nl) {
        const int n = ngrp * 8 + nl;
        // --- commit prefetched M_n to LDS (as is free: barrier passed) ---
        #pragma unroll
        for (int it = 0; it < 8; ++it) {
            const int id = it * 256 + t;
            const int row = id >> 4;
            const int koff = (id & 15) * 8;
            *(uint4*)&as[row * KP + koff] = pref[it];
        }
        if (t < DD) sv[t] = vws[n * DD + t];
        if (t == 0) sterm[nl] = termws[n];
        if (nl > 0 && t < 128) qbuf[(nl - 1) * 128 + t] = redbuf[t] + redbuf[128 + t];

        // --- issue next-M global loads; they fly under this iter's MFMA ---
        if (nl < 7) {
            const unsigned short* __restrict__ Mn1 =
                Mws + (size_t)(n + 1) * DD * DD;
            #pragma unroll
            for (int it = 0; it < 8; ++it) {
                const int id = it * 256 + t;
                const int row = id >> 4;
                const int koff = (id & 15) * 8;
                pref[it] = *(const uint4*)&Mn1[(size_t)row * DD + koff];
            }
        }
        __syncthreads();   // as + sv visible

        // --- MFMA: C[128i x 128b] split 2x2 over waves, K=128 ---
        f32x4 acc[4][4];
        #pragma unroll
        for (int it = 0; it < 4; ++it)
            #pragma unroll
            for (int bt = 0; bt < 4; ++bt) acc[it][bt] = zero;

        #pragma unroll
        for (int ks = 0; ks < 4; ++ks) {
            bf16x8 af[4];
            #pragma unroll
            for (int it = 0; it < 4; ++it) {
                const int row = wi * 64 + it * 16 + (lane & 15);
                const int k = ks * 32 + (lane >> 4) * 8;
                af[it] = *(const bf16x8*)&as[row * KP + k];
            }
            #pragma unroll
            for (int it = 0; it < 4; ++it)
                #pragma unroll
                for (int bt = 0; bt < 4; ++bt)
                    acc[it][bt] = __builtin_amdgcn_mfma_f32_16x16x32_bf16(
                        af[it], bf[bt][ks], acc[it][bt], 0, 0, 0);
        }

        // --- epilogue: p[b] += (y - v)^2 over this wave's 64 rows ---
        float p[4] = {0.0f, 0.0f, 0.0f, 0.0f};
        #pragma unroll
        for (int it = 0; it < 4; ++it) {
            const int rowbase = wi * 64 + it * 16 + (lane >> 4) * 4;  // C row = q*4+reg
            const f32x4 v4 = *(const f32x4*)&sv[rowbase];
            #pragma unroll
            for (int bt = 0; bt < 4; ++bt) {
                const f32x4 a = acc[it][bt];
                const float t0 = a.x - v4.x, t1 = a.y - v4.y;
                const float t2 = a.z - v4.z, t3 = a.w - v4.w;
                p[bt] += t0 * t0 + t1 * t1 + t2 * t2 + t3 * t3;
            }
        }
        #pragma unroll
        for (int bt = 0; bt < 4; ++bt) {
            float pv = p[bt];
            pv += __shfl_xor(pv, 16);
            pv += __shfl_xor(pv, 32);
            if (lane < 16) redbuf[wi * 128 + wb * 64 + bt * 16 + lane] = pv;
        }
        __syncthreads();   // as consumed; redbuf complete
    }

    if (t < 128) {
        qbuf[7 * 128 + t] = redbuf[t] + redbuf[128 + t];
        float o[8];
        #pragma unroll
        for (int j = 0; j < 8; ++j)
            o[j] = -0.5f * (sterm[j] + qbuf[j * 128 + t]);
        float* po = &out[(size_t)(bbase + t) * NN + ngrp * 8];
        *(float4*)&po[0] = make_float4(o[0], o[1], o[2], o[3]);
        *(float4*)&po[4] = make_float4(o[4], o[5], o[6], o[7]);
    }
}

// ---------------------------------------------------------------------------
// Fallback if workspace is too small: direct per-(b,n) solve (R2 path).
// ---------------------------------------------------------------------------
__global__ __launch_bounds__(256, 2)
void emission_solve_fb(const float* __restrict__ xin,
                       const float* __restrict__ means,
                       const float* __restrict__ chol,
                       float* __restrict__ out)
{
    const int n = blockIdx.y;
    const int t = threadIdx.x;
    const int b = blockIdx.x * 256 + t;
    const float* __restrict__ Ln = chol + (size_t)n * DD * DD;

    __shared__ float s_invd[DD];
    __shared__ float s_mu[DD];
    __shared__ float s_part[4];

    float raw = 0.0f;
    if (t < DD) {
        raw = Ln[t * DD + t];
        s_invd[t] = 1.0f / expf(raw);
        s_mu[t] = means[n * DD + t];
    }
    float v = raw;
    #pragma unroll
    for (int o = 32; o > 0; o >>= 1) v += __shfl_down(v, o);
    if ((t & 63) == 0) s_part[t >> 6] = v;
    __syncthreads();

    const float term = LOGC + 2.0f * (s_part[0] + s_part[1] + s_part[2] + s_part[3]);

    float y[DD];
    float quad = 0.0f;
    #pragma unroll
    for (int i = 0; i < DD; ++i) {
        const float xv = xin[(size_t)b * DD + i] - s_mu[i];
        float sA = 0.0f, sB = 0.0f;
        #pragma unroll
        for (int j = 0; j + 1 < i; j += 2) {
            sA = fmaf(Ln[i * DD + j], y[j], sA);
            sB = fmaf(Ln[i * DD + j + 1], y[j + 1], sB);
        }
        if (i & 1) sA = fmaf(Ln[i * DD + (i - 1)], y[i - 1], sA);
        const float s = xv - sA - sB;
        float yi = s * s_invd[i];
        yi = fminf(fmaxf(yi, -YCLAMP), YCLAMP);
        y[i] = yi;
        quad = fmaf(yi, yi, quad);
    }
    out[(size_t)b * NN + n] = -0.5f * (term + quad);
}

extern "C" void kernel_launch(void* const* d_in, const int* in_sizes, int n_in,
                              void* d_out, int out_size, void* d_ws, size_t ws_size,
                              hipStream_t stream) {
    const float* x     = (const float*)d_in[0];  // (8192,128)
    const float* means = (const float*)d_in[1];  // (64,128)
    const float* chol  = (const float*)d_in[2];  // (64,128,128)
    float* out = (float*)d_out;                  // (8192,64)

    const size_t needM = (size_t)NN * DD * DD * sizeof(unsigned short); // 2 MiB
    const size_t needV = (size_t)NN * DD * sizeof(float);               // 32 KiB
    const size_t needT = (size_t)NN * sizeof(float);

    if (ws_size >= needM + needV + needT) {
        unsigned short* Mws = (unsigned short*)d_ws;
        float* vws = (float*)((char*)d_ws + needM);
        float* tws = (float*)((char*)d_ws + needM + needV);
        solve_columns<<<dim3(33, NN), 256, 0, stream>>>(chol, means, Mws, vws, tws);
        emission_mfma<<<dim3(BB / 128, 8), 256, 0, stream>>>(x, Mws, vws, tws, out);
    } else {
        emission_solve_fb<<<dim3(BB / 256, NN), 256, 0, stream>>>(x, means, chol, out);
    }
}

// Round 6
// 100.407 us; speedup vs baseline: 1.4894x; 1.4894x over previous
//
#include <hip/hip_runtime.h>
#include <math.h>

#define DD 128
#define BB 8192
#define NN 64
#define LOGC 235.24826450039622f   // 128 * log(2*pi)
#define CLAMP_M 1.0e12f            // clamp on solve outputs: keeps all downstream f32 finite (no NaN)
#define YCLAMP 1.0e18f             // fallback-path clamp
#define KP 136                     // xs LDS pitch in bf16 (128+8)
#define PITCH 129                  // kernel-A LDS pitch in f32 (stride mod 32 = 1)

typedef __attribute__((ext_vector_type(8))) short bf16x8;   // 8 bf16 = 4 VGPRs
typedef __attribute__((ext_vector_type(4))) float f32x4;

__device__ __forceinline__ unsigned int f2bf(float x) {
    unsigned int u = __float_as_uint(x);
    return (u + 0x7FFFu + ((u >> 16) & 1u)) >> 16;
}
__device__ __forceinline__ unsigned int pack2(float lo, float hi) {
    return f2bf(lo) | (f2bf(hi) << 16);
}
__device__ __forceinline__ float clampM(float x) {
    return fminf(fmaxf(x, -CLAMP_M), CLAMP_M);
}
__device__ __forceinline__ float lane_bcast(float v, int j) {
    return __int_as_float(__builtin_amdgcn_readlane(__float_as_int(v), j));
}
// async 16B global->LDS (guide §5: width 16 verified on gfx950, m97)
__device__ __forceinline__ void gl_lds16(const unsigned short* g, unsigned short* l) {
    __builtin_amdgcn_global_load_lds(
        (const __attribute__((address_space(1))) void*)g,
        (__attribute__((address_space(3))) void*)l, 16, 0, 0);
}

// ---------------------------------------------------------------------------
// Kernel A (R6): 4 columns of M = L^-1 per wave. Grid (9, 64): grp 0..7 own
// columns grp*16 + w*4 .. +3; grp 8: wave0 solves RHS=mu -> vout, wave1 ->
// logdet. Triangular skip: wave starting at column c0 only runs steps j>=c0,
// and the block stages only LsT rows j >= grp*16. 4 interleaved chains hide
// the readlane->fma latency; the L row ds_read is shared by all 4 columns.
// ---------------------------------------------------------------------------
__global__ __launch_bounds__(256, 2)
void solve_columns(const float* __restrict__ chol,
                   const float* __restrict__ means,
                   unsigned short* __restrict__ Mout,  // (N,D,D) bf16 row-major
                   float* __restrict__ vout,           // (N,D)
                   float* __restrict__ termout)        // (N)
{
    const int n = blockIdx.y;
    const int grp = blockIdx.x;      // 0..8
    const int t = threadIdx.x;
    const int lane = t & 63;
    const int w = t >> 6;
    const float* __restrict__ Ln = chol + (size_t)n * DD * DD;

    const bool is_mu = (grp == 8);
    const int jmin = is_mu ? 0 : grp * 16;   // rows below this are never read

    __shared__ float LsT[DD][PITCH];   // [j][i] = (i>j) ? L[i][j] : 0
    __shared__ float s_invd[DD];
    __shared__ float s_raw[DD];
    __shared__ float ybuf[4][4][DD + 2];  // [wave][col][row]

    // --- stage L transposed + tril-masked; skip rows j < jmin ---
    #pragma unroll
    for (int it = 0; it < 16; ++it) {
        const int id = it * 256 + t;        // 4096 float4 chunks
        const int i = id >> 5;              // row of L
        const int j0 = (id & 31) * 4;       // col of L
        if (j0 < jmin) continue;            // LsT rows j<jmin never read
        if (i <= j0) {
            LsT[j0 + 0][i] = 0.0f;
            LsT[j0 + 1][i] = 0.0f;
            LsT[j0 + 2][i] = 0.0f;
            LsT[j0 + 3][i] = 0.0f;
        } else {
            const float4 vv = *(const float4*)(Ln + (size_t)i * DD + j0);
            LsT[j0 + 0][i] = (i > j0 + 0) ? vv.x : 0.0f;
            LsT[j0 + 1][i] = (i > j0 + 1) ? vv.y : 0.0f;
            LsT[j0 + 2][i] = (i > j0 + 2) ? vv.z : 0.0f;
            LsT[j0 + 3][i] = (i > j0 + 3) ? vv.w : 0.0f;
        }
    }
    if (t < DD) {
        const float raw = Ln[(size_t)t * DD + t];
        s_raw[t] = raw;
        s_invd[t] = __expf(-raw);           // 1/exp(raw): diag of L is exp(raw)
    }
    __syncthreads();

    if (is_mu) {
        if (w == 0) {
            // single-chain solve, RHS = mu
            float rl = means[(size_t)n * DD + lane];
            float rh = means[(size_t)n * DD + 64 + lane];
            #pragma unroll 4
            for (int j = 0; j < 64; ++j) {
                const float y = clampM(lane_bcast(rl, j) * s_invd[j]);
                rl = fmaf(-LsT[j][lane], y, rl);
                rh = fmaf(-LsT[j][64 + lane], y, rh);
            }
            #pragma unroll 4
            for (int j = 64; j < 128; ++j) {
                const float y = clampM(lane_bcast(rh, j - 64) * s_invd[j]);
                rh = fmaf(-LsT[j][64 + lane], y, rh);
            }
            vout[(size_t)n * DD + lane] = clampM(rl * s_invd[lane]);
            vout[(size_t)n * DD + 64 + lane] = clampM(rh * s_invd[64 + lane]);
        } else if (w == 1) {
            float v = s_raw[lane] + s_raw[64 + lane];
            #pragma unroll
            for (int o = 32; o > 0; o >>= 1) v += __shfl_down(v, o);
            if (lane == 0) termout[n] = LOGC + 2.0f * v;
        }
        return;
    }

    // --- 4 interleaved column chains: columns c0..c0+3 ---
    const int c0 = grp * 16 + w * 4;
    float r0l = (lane == c0 + 0) ? 1.0f : 0.0f;
    float r1l = (lane == c0 + 1) ? 1.0f : 0.0f;
    float r2l = (lane == c0 + 2) ? 1.0f : 0.0f;
    float r3l = (lane == c0 + 3) ? 1.0f : 0.0f;
    float r0h = (lane + 64 == c0 + 0) ? 1.0f : 0.0f;
    float r1h = (lane + 64 == c0 + 1) ? 1.0f : 0.0f;
    float r2h = (lane + 64 == c0 + 2) ? 1.0f : 0.0f;
    float r3h = (lane + 64 == c0 + 3) ? 1.0f : 0.0f;

    #pragma unroll 4
    for (int j = c0; j < 64; ++j) {
        const float invd = s_invd[j];
        const float Ll = LsT[j][lane];
        const float Lh = LsT[j][64 + lane];
        const float y0 = clampM(lane_bcast(r0l, j) * invd);
        const float y1 = clampM(lane_bcast(r1l, j) * invd);
        const float y2 = clampM(lane_bcast(r2l, j) * invd);
        const float y3 = clampM(lane_bcast(r3l, j) * invd);
        r0l = fmaf(-Ll, y0, r0l); r0h = fmaf(-Lh, y0, r0h);
        r1l = fmaf(-Ll, y1, r1l); r1h = fmaf(-Lh, y1, r1h);
        r2l = fmaf(-Ll, y2, r2l); r2h = fmaf(-Lh, y2, r2h);
        r3l = fmaf(-Ll, y3, r3l); r3h = fmaf(-Lh, y3, r3h);
    }
    #pragma unroll 4
    for (int j = (c0 > 64 ? c0 : 64); j < 128; ++j) {
        const float invd = s_invd[j];
        const float Lh = LsT[j][64 + lane];
        const float y0 = clampM(lane_bcast(r0h, j - 64) * invd);
        const float y1 = clampM(lane_bcast(r1h, j - 64) * invd);
        const float y2 = clampM(lane_bcast(r2h, j - 64) * invd);
        const float y3 = clampM(lane_bcast(r3h, j - 64) * invd);
        r0h = fmaf(-Lh, y0, r0h);
        r1h = fmaf(-Lh, y1, r1h);
        r2h = fmaf(-Lh, y2, r2h);
        r3h = fmaf(-Lh, y3, r3h);
    }

    // frozen-residual: final y_l = clamp(r_l * invd[l]) (zeros above c stay 0)
    const float i_lo = s_invd[lane], i_hi = s_invd[64 + lane];
    ybuf[w][0][lane] = clampM(r0l * i_lo); ybuf[w][0][64 + lane] = clampM(r0h * i_hi);
    ybuf[w][1][lane] = clampM(r1l * i_lo); ybuf[w][1][64 + lane] = clampM(r1h * i_hi);
    ybuf[w][2][lane] = clampM(r2l * i_lo); ybuf[w][2][64 + lane] = clampM(r2h * i_hi);
    ybuf[w][3][lane] = clampM(r3l * i_lo); ybuf[w][3][64 + lane] = clampM(r3h * i_hi);
    // same-wave DS ordering: no barrier needed (compiler waits lgkmcnt)

    // each lane writes 2 rows x 4 cols as bf16 (8B stores, c0 % 4 == 0)
    #pragma unroll
    for (int q = 0; q < 2; ++q) {
        const int i = 2 * lane + q;
        uint2 pk;
        pk.x = pack2(ybuf[w][0][i], ybuf[w][1][i]);
        pk.y = pack2(ybuf[w][2][i], ybuf[w][3][i]);
        *(uint2*)&Mout[((size_t)n * DD + i) * DD + c0] = pk;
    }
}

// ---------------------------------------------------------------------------
// Kernel B (R6): quad[b,n] = ||M_n x_b - v_n||^2, bf16 MFMA.
// M staging via async global_load_lds into double-buffered unpadded LDS with
// XOR-of-row chunk swizzle (wave-uniform-base constraint forbids padding).
// One barrier per n-iteration; next-M loads issue right after the barrier and
// land during the MFMA+epilogue, so the vmcnt(0) drain at the next barrier is
// free. No staging registers -> no spill (R5 post-mortem).
// ---------------------------------------------------------------------------
__global__ __launch_bounds__(256, 2)
void emission_mfma(const float* __restrict__ x,
                   const unsigned short* __restrict__ Mws,
                   const float* __restrict__ vws,
                   const float* __restrict__ termws,
                   float* __restrict__ out)
{
    const int btile = blockIdx.x;            // 64 tiles of 128 b
    const int ngrp = blockIdx.y;             // 8 groups of 8 n
    const int t = threadIdx.x;
    const int lane = t & 63;
    const int w = t >> 6;
    const int wi = w >> 1;                   // i-half
    const int wb = w & 1;                    // b-half

    // LDS arena: xs/P1 overlay | P0 | sv8 | qbuf | redbuf[2] | sterm
    __shared__ __align__(16) char smem[34816 + 32768 + 4096 + 4096 + 2048 + 32];
    unsigned short* xs = (unsigned short*)smem;              // 128*KP bf16
    unsigned short* P1 = (unsigned short*)smem;              // overlays xs
    unsigned short* P0 = (unsigned short*)(smem + 34816);
    float* sv8   = (float*)(smem + 34816 + 32768);           // [8][128]
    float* qbuf  = (float*)(smem + 34816 + 32768 + 4096);    // [8][128]
    float* redbuf = (float*)(smem + 34816 + 32768 + 8192);   // [2][256]
    float* sterm = (float*)(smem + 34816 + 32768 + 8192 + 2048); // [8]

    const int bbase = btile * 128;
    const unsigned short* __restrict__ Mbase = Mws + (size_t)(ngrp * 8) * DD * DD;

    // async-stage one 128x128 bf16 M tile into Pbuf with XOR chunk swizzle:
    // LDS chunk slot s holds global chunk (row = s>>4, kc = (s&15) ^ (row&15)).
    // Wave w, inst k covers slots w*512 + k*64 + lane.
    auto stage_M = [&](const unsigned short* Mn, unsigned short* Pbuf) {
        #pragma unroll
        for (int k = 0; k < 8; ++k) {
            const int s = w * 512 + k * 64 + lane;
            const int row = s >> 4;
            const int kc = (s & 15) ^ (row & 15);
            gl_lds16(Mn + (size_t)row * DD + kc * 8,
                     Pbuf + (size_t)(w * 512 + k * 64) * 8);
        }
    };

    // --- prologue: stage x (f32->bf16), sv8, sterm; issue M0 -> P0 ---
    #pragma unroll
    for (int it = 0; it < 8; ++it) {
        const int id = it * 256 + t;
        const int brow = id >> 4;
        const int koff = (id & 15) * 8;
        const float4* px = (const float4*)(x + (size_t)(bbase + brow) * DD + koff);
        const float4 a = px[0], b = px[1];
        uint4 p;
        p.x = pack2(a.x, a.y);
        p.y = pack2(a.z, a.w);
        p.z = pack2(b.x, b.y);
        p.w = pack2(b.z, b.w);
        *(uint4*)&xs[brow * KP + koff] = p;
    }
    *(float4*)&sv8[4 * t] = *(const float4*)&vws[(size_t)ngrp * 8 * DD + 4 * t];
    if (t < 8) sterm[t] = termws[ngrp * 8 + t];
    stage_M(Mbase, P0);
    __syncthreads();   // xs + sv8 visible (M0 drained here too)

    // --- preload B-operand frags (x) to registers ---
    bf16x8 bf[4][4];
    #pragma unroll
    for (int bt = 0; bt < 4; ++bt)
        #pragma unroll
        for (int ks = 0; ks < 4; ++ks) {
            const int col = wb * 64 + bt * 16 + (lane & 15);
            const int k = ks * 32 + (lane >> 4) * 8;
            bf[bt][ks] = *(const bf16x8*)&xs[col * KP + k];
        }
    __syncthreads();   // all frags read; xs region free for P1

    const f32x4 zero = {0.0f, 0.0f, 0.0f, 0.0f};

    for (int nl = 0; nl < 8; ++nl) {
        // issue next-M loads; they fly under this iteration's MFMA+epilogue
        if (nl < 7)
            stage_M(Mbase + (size_t)(nl + 1) * DD * DD, ((nl + 1) & 1) ? P1 : P0);
        // fold previous iteration's reduction (redbuf parity-buffered)
        if (nl > 0 && t < 128) {
            float* rb = redbuf + ((nl - 1) & 1) * 256;
            qbuf[(nl - 1) * 128 + t] = rb[t] + rb[128 + t];
        }

        const unsigned short* Pc = (nl & 1) ? P1 : P0;

        f32x4 acc[4][4];
        #pragma unroll
        for (int it = 0; it < 4; ++it)
            #pragma unroll
            for (int bt = 0; bt < 4; ++bt) acc[it][bt] = zero;

        #pragma unroll
        for (int ks = 0; ks < 4; ++ks) {
            bf16x8 af[4];
            #pragma unroll
            for (int it = 0; it < 4; ++it) {
                const int row = wi * 64 + it * 16 + (lane & 15);
                const int kchunk = ks * 4 + (lane >> 4);
                af[it] = *(const bf16x8*)((const char*)Pc + row * 256 +
                                          ((kchunk ^ (row & 15)) * 16));
            }
            #pragma unroll
            for (int it = 0; it < 4; ++it)
                #pragma unroll
                for (int bt = 0; bt < 4; ++bt)
                    acc[it][bt] = __builtin_amdgcn_mfma_f32_16x16x32_bf16(
                        af[it], bf[bt][ks], acc[it][bt], 0, 0, 0);
        }

        // epilogue: p[b] += (y - v)^2 over this wave's 64 rows
        float p[4] = {0.0f, 0.0f, 0.0f, 0.0f};
        #pragma unroll
        for (int it = 0; it < 4; ++it) {
            const int rowbase = wi * 64 + it * 16 + (lane >> 4) * 4;  // C row = q*4+reg
            const f32x4 v4 = *(const f32x4*)&sv8[nl * 128 + rowbase];
            #pragma unroll
            for (int bt = 0; bt < 4; ++bt) {
                const f32x4 a = acc[it][bt];
                const float t0 = a.x - v4.x, t1 = a.y - v4.y;
                const float t2 = a.z - v4.z, t3 = a.w - v4.w;
                p[bt] += t0 * t0 + t1 * t1 + t2 * t2 + t3 * t3;
            }
        }
        float* rb = redbuf + (nl & 1) * 256;
        #pragma unroll
        for (int bt = 0; bt < 4; ++bt) {
            float pv = p[bt];
            pv += __shfl_xor(pv, 16);
            pv += __shfl_xor(pv, 32);
            if (lane < 16) rb[wi * 128 + wb * 64 + bt * 16 + lane] = pv;
        }
        __syncthreads();   // drains next-M loads (covered by compute); redbuf ready
    }

    if (t < 128) {
        qbuf[7 * 128 + t] = redbuf[256 + t] + redbuf[256 + 128 + t];  // nl=7 parity 1
        float o[8];
        #pragma unroll
        for (int j = 0; j < 8; ++j)
            o[j] = -0.5f * (sterm[j] + qbuf[j * 128 + t]);
        float* po = &out[(size_t)(bbase + t) * NN + ngrp * 8];
        *(float4*)&po[0] = make_float4(o[0], o[1], o[2], o[3]);
        *(float4*)&po[4] = make_float4(o[4], o[5], o[6], o[7]);
    }
}

// ---------------------------------------------------------------------------
// Fallback if workspace is too small: direct per-(b,n) solve (R2 path).
// ---------------------------------------------------------------------------
__global__ __launch_bounds__(256, 2)
void emission_solve_fb(const float* __restrict__ xin,
                       const float* __restrict__ means,
                       const float* __restrict__ chol,
                       float* __restrict__ out)
{
    const int n = blockIdx.y;
    const int t = threadIdx.x;
    const int b = blockIdx.x * 256 + t;
    const float* __restrict__ Ln = chol + (size_t)n * DD * DD;

    __shared__ float s_invd[DD];
    __shared__ float s_mu[DD];
    __shared__ float s_part[4];

    float raw = 0.0f;
    if (t < DD) {
        raw = Ln[t * DD + t];
        s_invd[t] = 1.0f / expf(raw);
        s_mu[t] = means[n * DD + t];
    }
    float v = raw;
    #pragma unroll
    for (int o = 32; o > 0; o >>= 1) v += __shfl_down(v, o);
    if ((t & 63) == 0) s_part[t >> 6] = v;
    __syncthreads();

    const float term = LOGC + 2.0f * (s_part[0] + s_part[1] + s_part[2] + s_part[3]);

    float y[DD];
    float quad = 0.0f;
    #pragma unroll
    for (int i = 0; i < DD; ++i) {
        const float xv = xin[(size_t)b * DD + i] - s_mu[i];
        float sA = 0.0f, sB = 0.0f;
        #pragma unroll
        for (int j = 0; j + 1 < i; j += 2) {
            sA = fmaf(Ln[i * DD + j], y[j], sA);
            sB = fmaf(Ln[i * DD + j + 1], y[j + 1], sB);
        }
        if (i & 1) sA = fmaf(Ln[i * DD + (i - 1)], y[i - 1], sA);
        const float s = xv - sA - sB;
        float yi = s * s_invd[i];
        yi = fminf(fmaxf(yi, -YCLAMP), YCLAMP);
        y[i] = yi;
        quad = fmaf(yi, yi, quad);
    }
    out[(size_t)b * NN + n] = -0.5f * (term + quad);
}

extern "C" void kernel_launch(void* const* d_in, const int* in_sizes, int n_in,
                              void* d_out, int out_size, void* d_ws, size_t ws_size,
                              hipStream_t stream) {
    const float* x     = (const float*)d_in[0];  // (8192,128)
    const float* means = (const float*)d_in[1];  // (64,128)
    const float* chol  = (const float*)d_in[2];  // (64,128,128)
    float* out = (float*)d_out;                  // (8192,64)

    const size_t needM = (size_t)NN * DD * DD * sizeof(unsigned short); // 2 MiB
    const size_t needV = (size_t)NN * DD * sizeof(float);               // 32 KiB
    const size_t needT = (size_t)NN * sizeof(float);

    if (ws_size >= needM + needV + needT) {
        unsigned short* Mws = (unsigned short*)d_ws;
        float* vws = (float*)((char*)d_ws + needM);
        float* tws = (float*)((char*)d_ws + needM + needV);
        solve_columns<<<dim3(9, NN), 256, 0, stream>>>(chol, means, Mws, vws, tws);
        emission_mfma<<<dim3(BB / 128, 8), 256, 0, stream>>>(x, Mws, vws, tws, out);
    } else {
        emission_solve_fb<<<dim3(BB / 256, NN), 256, 0, stream>>>(x, means, chol, out);
    }
}